// Round 1
// baseline (1544.979 us; speedup 1.0000x reference)
//
#include <hip/hip_runtime.h>
#include <hip/hip_bf16.h>
#include <math.h>

#define D_DIM 1024
#define L_DIM 4096
#define B_DIM 2
#define K_DIM 256           // D/4
#define N6    1536          // K*6
#define M_ROWS 8192         // B*L
#define CHUNKS 256
#define CHUNK_LEN 16

// ---------------- rotor helpers ----------------
__device__ __forceinline__ void rotor_from_angles(const float a[6], float& s, float b[6]) {
    float m2 = a[0]*a[0] + a[1]*a[1] + a[2]*a[2] + a[3]*a[3] + a[4]*a[4] + a[5]*a[5];
    float mag = fmaxf(sqrtf(m2), 1e-8f);
    float sn, cs;
    __sincosf(mag, &sn, &cs);
    // use precise versions for safety:
    sn = sinf(mag); cs = cosf(mag);
    s = cs;
    float f = sn / mag;
    #pragma unroll
    for (int i = 0; i < 6; ++i) b[i] = f * a[i];
}

__device__ __forceinline__ void apply_rotor(float s, const float b[6], const float v[4], float o[4]) {
    float t12 = b[0], t13 = b[1], t14 = b[2], t23 = b[3], t24 = b[4], t34 = b[5];
    float v1 = v[0], v2 = v[1], v3 = v[2], v4 = v[3];
    float s2 = s * s;
    float ts = 2.0f * s;
    o[0] = v1 * (s2 - t12*t12 - t13*t13 - t14*t14) + ts * ( v2*t12 + v3*t13 + v4*t14);
    o[1] = v2 * (s2 - t12*t12 - t23*t23 - t24*t24) + ts * (-v1*t12 + v3*t23 + v4*t24);
    o[2] = v3 * (s2 - t13*t13 - t23*t23 - t34*t34) + ts * (-v1*t13 - v2*t23 + v4*t34);
    o[3] = v4 * (s2 - t14*t14 - t24*t24 - t34*t34) + ts * (-v1*t14 - v2*t24 - v3*t34);
}

// ---------------- GEMM ----------------
// C[M,N] = act(A[M,K] @ W[K,N] + bias) (+ resid)
// ACT: 0=none, 1=exact gelu, 2=tanh(x)*pi/2
#define BM 128
#define BN 64
#define BKT 16

template<int ACT, bool RESID>
__global__ __launch_bounds__(256)
void gemm_kernel(const float* __restrict__ A, const float* __restrict__ W,
                 const float* __restrict__ bias, const float* __restrict__ resid,
                 float* __restrict__ C, int M, int N, int Kd)
{
    __shared__ float As[BKT][BM];
    __shared__ float Bs[BKT][BN];
    const int bm = blockIdx.x * BM;
    const int bn = blockIdx.y * BN;
    const int tid = threadIdx.x;
    const int tx = tid & 15;
    const int ty = tid >> 4;
    const int arow = tid >> 1;          // 0..127
    const int acol = (tid & 1) * 8;     // 0 or 8
    const int brow = tid >> 4;          // 0..15
    const int bcol = (tid & 15) * 4;    // 0..60

    const float* Ap = A + (size_t)(bm + arow) * Kd + acol;
    const float* Wp = W + (size_t)brow * N + bn + bcol;

    float acc[8][4];
    #pragma unroll
    for (int i = 0; i < 8; ++i)
        #pragma unroll
        for (int j = 0; j < 4; ++j) acc[i][j] = 0.0f;

    for (int k0 = 0; k0 < Kd; k0 += BKT) {
        float4 a0 = *(const float4*)(Ap + k0);
        float4 a1 = *(const float4*)(Ap + k0 + 4);
        float4 bv = *(const float4*)(Wp + (size_t)k0 * N);
        __syncthreads();
        As[acol + 0][arow] = a0.x;
        As[acol + 1][arow] = a0.y;
        As[acol + 2][arow] = a0.z;
        As[acol + 3][arow] = a0.w;
        As[acol + 4][arow] = a1.x;
        As[acol + 5][arow] = a1.y;
        As[acol + 6][arow] = a1.z;
        As[acol + 7][arow] = a1.w;
        *(float4*)&Bs[brow][bcol] = bv;
        __syncthreads();
        #pragma unroll
        for (int kk = 0; kk < BKT; ++kk) {
            float4 aA = *(const float4*)&As[kk][ty * 8];
            float4 aB = *(const float4*)&As[kk][ty * 8 + 4];
            float4 bb = *(const float4*)&Bs[kk][tx * 4];
            float am[8] = {aA.x, aA.y, aA.z, aA.w, aB.x, aB.y, aB.z, aB.w};
            float bn_[4] = {bb.x, bb.y, bb.z, bb.w};
            #pragma unroll
            for (int i = 0; i < 8; ++i)
                #pragma unroll
                for (int j = 0; j < 4; ++j)
                    acc[i][j] = fmaf(am[i], bn_[j], acc[i][j]);
        }
    }

    float4 bias4 = *(const float4*)(bias + bn + tx * 4);
    float barr[4] = {bias4.x, bias4.y, bias4.z, bias4.w};
    #pragma unroll
    for (int i = 0; i < 8; ++i) {
        int row = bm + ty * 8 + i;
        float o[4];
        #pragma unroll
        for (int j = 0; j < 4; ++j) {
            float v = acc[i][j] + barr[j];
            if (ACT == 1) v = 0.5f * v * (1.0f + erff(v * 0.70710678118654752f));
            else if (ACT == 2) v = tanhf(v) * 1.57079632679489662f;
            o[j] = v;
        }
        size_t off = (size_t)row * N + bn + tx * 4;
        float4 ov = make_float4(o[0], o[1], o[2], o[3]);
        if (RESID) {
            float4 rv = *(const float4*)(resid + off);
            ov.x += rv.x; ov.y += rv.y; ov.z += rv.z; ov.w += rv.w;
        }
        *(float4*)(C + off) = ov;
    }
}

// ---------------- rotate value by key rotor (in place) ----------------
__global__ __launch_bounds__(256)
void rotate_value_kernel(const float* __restrict__ angles, float* __restrict__ val)
{
    int idx = blockIdx.x * 256 + threadIdx.x;   // 0 .. M_ROWS*K_DIM-1
    int row = idx >> 8;
    int k = idx & 255;
    const float* ap = angles + (size_t)row * N6 + k * 6;
    float2 a01 = *(const float2*)(ap);
    float2 a23 = *(const float2*)(ap + 2);
    float2 a45 = *(const float2*)(ap + 4);
    float a[6] = {a01.x, a01.y, a23.x, a23.y, a45.x, a45.y};
    float s, b[6];
    rotor_from_angles(a, s, b);
    float* vp = val + (size_t)row * D_DIM + k * 4;
    float4 v4 = *(const float4*)vp;
    float v[4] = {v4.x, v4.y, v4.z, v4.w}, o[4];
    apply_rotor(s, b, v, o);
    *(float4*)vp = make_float4(o[0], o[1], o[2], o[3]);
}

// ---------------- scan phase 1: per-chunk sums ----------------
__global__ __launch_bounds__(256)
void chunk_sum_kernel(const float* __restrict__ rot, float4* __restrict__ sums)
{
    int bc = blockIdx.x;            // 0..B*CHUNKS-1
    int b = bc >> 8, c = bc & 255;
    int k = threadIdx.x;
    const float* p = rot + ((size_t)(b * L_DIM + c * CHUNK_LEN)) * D_DIM + k * 4;
    float4 acc = make_float4(0.f, 0.f, 0.f, 0.f);
    #pragma unroll
    for (int i = 0; i < CHUNK_LEN; ++i) {
        float4 v = *(const float4*)(p + (size_t)i * D_DIM);
        acc.x += v.x; acc.y += v.y; acc.z += v.z; acc.w += v.w;
    }
    sums[(size_t)bc * 256 + k] = acc;
}

// ---------------- scan phase 2: exclusive scan of chunk sums ----------------
__global__ __launch_bounds__(256)
void scan_chunks_kernel(const float4* __restrict__ sums, float4* __restrict__ carry)
{
    int b = blockIdx.x >> 8;        // grid = B*K_DIM
    int k = blockIdx.x & 255;
    int c = threadIdx.x;            // chunk index
    __shared__ float4 sh[CHUNKS];
    float4 v = sums[((size_t)(b * CHUNKS + c)) * 256 + k];
    sh[c] = v;
    __syncthreads();
    for (int off = 1; off < CHUNKS; off <<= 1) {
        float4 t = make_float4(0.f, 0.f, 0.f, 0.f);
        if (c >= off) t = sh[c - off];
        __syncthreads();
        v.x += t.x; v.y += t.y; v.z += t.z; v.w += t.w;
        sh[c] = v;
        __syncthreads();
    }
    float4 ex = make_float4(0.f, 0.f, 0.f, 0.f);
    if (c > 0) ex = sh[c - 1];
    carry[((size_t)(b * CHUNKS + c)) * 256 + k] = ex;
}

// ---------------- scan phase 3: running sum + reversed query rotor + 1/sqrt(t) ----------------
__global__ __launch_bounds__(256)
void scan_apply_kernel(const float* __restrict__ rot, const float4* __restrict__ carry,
                       const float* __restrict__ qang, float* __restrict__ outr)
{
    int bc = blockIdx.x;
    int b = bc >> 8, c = bc & 255;
    int k = threadIdx.x;
    float4 run = carry[(size_t)bc * 256 + k];
    for (int i = 0; i < CHUNK_LEN; ++i) {
        int l = c * CHUNK_LEN + i;
        size_t roff = ((size_t)(b * L_DIM + l)) * D_DIM + k * 4;
        float4 rv = *(const float4*)(rot + roff);
        run.x += rv.x; run.y += rv.y; run.z += rv.z; run.w += rv.w;
        const float* ap = qang + ((size_t)(b * L_DIM + l)) * N6 + k * 6;
        float2 a01 = *(const float2*)(ap);
        float2 a23 = *(const float2*)(ap + 2);
        float2 a45 = *(const float2*)(ap + 4);
        float a[6] = {a01.x, a01.y, a23.x, a23.y, a45.x, a45.y};
        float s, bb[6];
        rotor_from_angles(a, s, bb);
        #pragma unroll
        for (int t = 0; t < 6; ++t) bb[t] = -bb[t];
        float mem[4] = {run.x, run.y, run.z, run.w}, o[4];
        apply_rotor(s, bb, mem, o);
        float inv = 1.0f / sqrtf((float)(l + 1));
        *(float4*)(outr + roff) = make_float4(o[0] * inv, o[1] * inv, o[2] * inv, o[3] * inv);
    }
}

// ---------------- LayerNorm (in place, one block per row) ----------------
__global__ __launch_bounds__(256)
void layernorm_kernel(float* __restrict__ r, const float* __restrict__ g, const float* __restrict__ b)
{
    int row = blockIdx.x;
    int t = threadIdx.x;
    float* p = r + (size_t)row * D_DIM + t * 4;
    float4 v = *(const float4*)p;
    float s = v.x + v.y + v.z + v.w;
    float q = v.x * v.x + v.y * v.y + v.z * v.z + v.w * v.w;
    #pragma unroll
    for (int off = 1; off < 64; off <<= 1) {
        s += __shfl_xor(s, off);
        q += __shfl_xor(q, off);
    }
    __shared__ float ss[4], qq[4];
    int wave = t >> 6, lane = t & 63;
    if (lane == 0) { ss[wave] = s; qq[wave] = q; }
    __syncthreads();
    s = ss[0] + ss[1] + ss[2] + ss[3];
    q = qq[0] + qq[1] + qq[2] + qq[3];
    float mu = s * (1.0f / 1024.0f);
    float var = q * (1.0f / 1024.0f) - mu * mu;
    float rstd = 1.0f / sqrtf(var + 1e-5f);
    float4 gv = *(const float4*)(g + t * 4);
    float4 bv = *(const float4*)(b + t * 4);
    v.x = (v.x - mu) * rstd * gv.x + bv.x;
    v.y = (v.y - mu) * rstd * gv.y + bv.y;
    v.z = (v.z - mu) * rstd * gv.z + bv.z;
    v.w = (v.w - mu) * rstd * gv.w + bv.w;
    *(float4*)p = v;
}

extern "C" void kernel_launch(void* const* d_in, const int* in_sizes, int n_in,
                              void* d_out, int out_size, void* d_ws, size_t ws_size,
                              hipStream_t stream)
{
    const float* x   = (const float*)d_in[0];
    const float* wk1 = (const float*)d_in[1];
    const float* bk1 = (const float*)d_in[2];
    const float* wk2 = (const float*)d_in[3];
    const float* bk2 = (const float*)d_in[4];
    const float* wq1 = (const float*)d_in[5];
    const float* bq1 = (const float*)d_in[6];
    const float* wq2 = (const float*)d_in[7];
    const float* bq2 = (const float*)d_in[8];
    const float* wv  = (const float*)d_in[9];
    const float* bv  = (const float*)d_in[10];
    const float* lng = (const float*)d_in[11];
    const float* lnb = (const float*)d_in[12];
    const float* wo  = (const float*)d_in[13];
    const float* bo  = (const float*)d_in[14];
    float* out = (float*)d_out;

    char* ws = (char*)d_ws;
    float*  bufA  = (float*)(ws);                          // 32 MB: hk / hq / retrieved / rn
    float*  bufB  = (float*)(ws + ((size_t)32 << 20));     // 48 MB: ak / aq
    float*  bufC  = (float*)(ws + ((size_t)80 << 20));     // 32 MB: value -> rotated
    float4* sums  = (float4*)(ws + ((size_t)112 << 20));   // 2 MB
    float4* carry = (float4*)(ws + ((size_t)114 << 20));   // 2 MB

    dim3 blk(256);
    dim3 g1(M_ROWS / BM, D_DIM / BN);    // (64,16)
    dim3 g2(M_ROWS / BM, N6 / BN);       // (64,24)

    // hk = gelu(x@wk1 + bk1)
    gemm_kernel<1, false><<<g1, blk, 0, stream>>>(x, wk1, bk1, nullptr, bufA, M_ROWS, D_DIM, D_DIM);
    // ak = tanh(hk@wk2 + bk2) * pi/2
    gemm_kernel<2, false><<<g2, blk, 0, stream>>>(bufA, wk2, bk2, nullptr, bufB, M_ROWS, N6, D_DIM);
    // value = x@wv + bv
    gemm_kernel<0, false><<<g1, blk, 0, stream>>>(x, wv, bv, nullptr, bufC, M_ROWS, D_DIM, D_DIM);
    // rotated = apply_rotor(rotor(ak), value)   (in place on bufC)
    rotate_value_kernel<<<dim3(M_ROWS * K_DIM / 256), blk, 0, stream>>>(bufB, bufC);
    // hq = gelu(x@wq1 + bq1)
    gemm_kernel<1, false><<<g1, blk, 0, stream>>>(x, wq1, bq1, nullptr, bufA, M_ROWS, D_DIM, D_DIM);
    // aq = tanh(hq@wq2 + bq2) * pi/2
    gemm_kernel<2, false><<<g2, blk, 0, stream>>>(bufA, wq2, bq2, nullptr, bufB, M_ROWS, N6, D_DIM);
    // cumsum (3-phase) + reversed query rotor + 1/sqrt(t)
    chunk_sum_kernel<<<dim3(B_DIM * CHUNKS), blk, 0, stream>>>(bufC, sums);
    scan_chunks_kernel<<<dim3(B_DIM * K_DIM), blk, 0, stream>>>(sums, carry);
    scan_apply_kernel<<<dim3(B_DIM * CHUNKS), blk, 0, stream>>>(bufC, carry, bufB, bufA);
    // LayerNorm in place
    layernorm_kernel<<<dim3(M_ROWS), blk, 0, stream>>>(bufA, lng, lnb);
    // out = x + rn@wo + bo
    gemm_kernel<0, true><<<g1, blk, 0, stream>>>(bufA, wo, bo, x, out, M_ROWS, D_DIM, D_DIM);
}

// Round 2
// 309.143 us; speedup vs baseline: 4.9976x; 4.9976x over previous
//
#include <hip/hip_runtime.h>
#include <hip/hip_bf16.h>
#include <math.h>

#define D_DIM 1024
#define L_DIM 4096
#define B_DIM 2
#define K_DIM 256           // D/4
#define N6    1536          // K*6
#define M_ROWS 8192         // B*L
#define CHUNKS 256
#define CHUNK_LEN 16

typedef __attribute__((ext_vector_type(8))) short short8;
typedef __attribute__((ext_vector_type(4))) float f32x4;

__device__ __forceinline__ void gload_lds16(const void* g, void* l) {
    __builtin_amdgcn_global_load_lds(
        (const __attribute__((address_space(1))) unsigned int*)g,
        (__attribute__((address_space(3))) unsigned int*)l,
        16, 0, 0);
}

__device__ __forceinline__ unsigned short f2bf(float v) {
    __hip_bfloat16 h = __float2bfloat16(v);
    return *(unsigned short*)&h;
}

// ---------------- rotor helpers ----------------
__device__ __forceinline__ void rotor_from_angles(const float a[6], float& s, float b[6]) {
    float m2 = a[0]*a[0] + a[1]*a[1] + a[2]*a[2] + a[3]*a[3] + a[4]*a[4] + a[5]*a[5];
    float mag = fmaxf(sqrtf(m2), 1e-8f);
    s = cosf(mag);
    float f = sinf(mag) / mag;
    #pragma unroll
    for (int i = 0; i < 6; ++i) b[i] = f * a[i];
}

__device__ __forceinline__ void apply_rotor(float s, const float b[6], const float v[4], float o[4]) {
    float t12 = b[0], t13 = b[1], t14 = b[2], t23 = b[3], t24 = b[4], t34 = b[5];
    float v1 = v[0], v2 = v[1], v3 = v[2], v4 = v[3];
    float s2 = s * s;
    float ts = 2.0f * s;
    o[0] = v1 * (s2 - t12*t12 - t13*t13 - t14*t14) + ts * ( v2*t12 + v3*t13 + v4*t14);
    o[1] = v2 * (s2 - t12*t12 - t23*t23 - t24*t24) + ts * (-v1*t12 + v3*t23 + v4*t24);
    o[2] = v3 * (s2 - t13*t13 - t23*t23 - t34*t34) + ts * (-v1*t13 - v2*t23 + v4*t34);
    o[3] = v4 * (s2 - t14*t14 - t24*t24 - t34*t34) + ts * (-v1*t14 - v2*t24 - v3*t34);
}

// ---------------- weight transpose + bf16 convert: W[K][N] -> Wt[N][K] ----------------
__global__ __launch_bounds__(256)
void transpose_cvt_kernel(const float* __restrict__ W, __hip_bfloat16* __restrict__ Wt,
                          int Kd, int N)
{
    __shared__ float sh[32][33];
    int n0 = blockIdx.x * 32, k0 = blockIdx.y * 32;
    int tx = threadIdx.x & 31, ty = threadIdx.x >> 5;   // ty 0..7
    #pragma unroll
    for (int i = 0; i < 32; i += 8)
        sh[ty + i][tx] = W[(size_t)(k0 + ty + i) * N + n0 + tx];
    __syncthreads();
    #pragma unroll
    for (int i = 0; i < 32; i += 8)
        Wt[(size_t)(n0 + ty + i) * Kd + k0 + tx] = __float2bfloat16(sh[tx][ty + i]);
}

// ---------------- fp32 -> bf16 convert (8 elems/thread) ----------------
__global__ __launch_bounds__(256)
void cvt_bf16_kernel(const float* __restrict__ in, __hip_bfloat16* __restrict__ out)
{
    size_t i = ((size_t)blockIdx.x * 256 + threadIdx.x) * 8;
    float4 v0 = *(const float4*)(in + i);
    float4 v1 = *(const float4*)(in + i + 4);
    union { unsigned short u[8]; uint4 v; } pk;
    pk.u[0] = f2bf(v0.x); pk.u[1] = f2bf(v0.y); pk.u[2] = f2bf(v0.z); pk.u[3] = f2bf(v0.w);
    pk.u[4] = f2bf(v1.x); pk.u[5] = f2bf(v1.y); pk.u[6] = f2bf(v1.z); pk.u[7] = f2bf(v1.w);
    *(uint4*)(out + i) = pk.v;
}

// ---------------- bf16 MFMA GEMM ----------------
// C[M,N] = epi(A[M,K] @ Bt[N,K]^T + bias)
// ACT: 0=none, 1=exact gelu, 2=tanh(x)*pi/2
// OUTM: 0=f32, 1=bf16, 2=f32 + resid
template<int ACT, int OUTM>
__global__ __launch_bounds__(256)
void mfma_gemm_kernel(const __hip_bfloat16* __restrict__ A,
                      const __hip_bfloat16* __restrict__ Bt,
                      const float* __restrict__ bias,
                      const float* __restrict__ resid,
                      void* __restrict__ Cout,
                      int M, int N, int Kd)
{
    __shared__ short As[128 * 32];
    __shared__ short Bs[128 * 32];
    const int tid = threadIdx.x;
    const int l = tid & 63;
    const int w = tid >> 6;
    const int wr = w >> 1, wc = w & 1;       // 2x2 waves, 64x64 each
    const int bm = blockIdx.x * 128;
    const int bn = blockIdx.y * 128;

    // staging: thread t handles 8 contiguous bf16; linear LDS [128][32]
    const int er = (tid * 8) >> 5;           // 0..63
    const int ec = (tid * 8) & 31;
    const __hip_bfloat16* gA0 = A  + (size_t)(bm + er) * Kd + ec;
    const __hip_bfloat16* gA1 = A  + (size_t)(bm + 64 + er) * Kd + ec;
    const __hip_bfloat16* gB0 = Bt + (size_t)(bn + er) * Kd + ec;
    const __hip_bfloat16* gB1 = Bt + (size_t)(bn + 64 + er) * Kd + ec;
    short* lA0 = As + tid * 8;
    short* lA1 = As + 2048 + tid * 8;
    short* lB0 = Bs + tid * 8;
    short* lB1 = Bs + 2048 + tid * 8;

    f32x4 acc[4][4];
    #pragma unroll
    for (int i = 0; i < 4; ++i)
        #pragma unroll
        for (int j = 0; j < 4; ++j)
            acc[i][j] = (f32x4){0.f, 0.f, 0.f, 0.f};

    const int fr = l & 15;   // fragment row index within 16
    const int fq = l >> 4;   // quarter 0..3
    const int aoff = (wr * 64 + fr) * 32 + fq * 8;
    const int boff = (wc * 64 + fr) * 32 + fq * 8;

    for (int k0 = 0; k0 < Kd; k0 += 32) {
        gload_lds16(gA0 + k0, lA0);
        gload_lds16(gA1 + k0, lA1);
        gload_lds16(gB0 + k0, lB0);
        gload_lds16(gB1 + k0, lB1);
        __syncthreads();                     // vmcnt(0) drain + barrier
        short8 af[4], bfr[4];
        #pragma unroll
        for (int i = 0; i < 4; ++i) {
            af[i]  = *(const short8*)&As[aoff + i * 512];
            bfr[i] = *(const short8*)&Bs[boff + i * 512];
        }
        #pragma unroll
        for (int i = 0; i < 4; ++i)
            #pragma unroll
            for (int j = 0; j < 4; ++j)
                acc[i][j] = __builtin_amdgcn_mfma_f32_16x16x32_bf16(af[i], bfr[j], acc[i][j], 0, 0, 0);
        __syncthreads();                     // all reads done before next overwrite
    }

    // epilogue: C/D layout col = lane&15, row = (lane>>4)*4 + reg
    #pragma unroll
    for (int i = 0; i < 4; ++i) {
        int row = bm + wr * 64 + i * 16 + fq * 4;
        #pragma unroll
        for (int j = 0; j < 4; ++j) {
            int col = bn + wc * 64 + j * 16 + fr;
            float bsv = bias[col];
            #pragma unroll
            for (int v = 0; v < 4; ++v) {
                float val = acc[i][j][v] + bsv;
                if (ACT == 1) val = 0.5f * val * (1.0f + erff(val * 0.70710678118654752f));
                else if (ACT == 2) val = tanhf(val) * 1.57079632679489662f;
                size_t off = (size_t)(row + v) * N + col;
                if (OUTM == 1) {
                    ((__hip_bfloat16*)Cout)[off] = __float2bfloat16(val);
                } else if (OUTM == 2) {
                    ((float*)Cout)[off] = val + resid[off];
                } else {
                    ((float*)Cout)[off] = val;
                }
            }
        }
    }
}

// ---------------- rotate value by key rotor (in place) ----------------
__global__ __launch_bounds__(256)
void rotate_value_kernel(const float* __restrict__ angles, float* __restrict__ val)
{
    int idx = blockIdx.x * 256 + threadIdx.x;
    int row = idx >> 8;
    int k = idx & 255;
    const float* ap = angles + (size_t)row * N6 + k * 6;
    float2 a01 = *(const float2*)(ap);
    float2 a23 = *(const float2*)(ap + 2);
    float2 a45 = *(const float2*)(ap + 4);
    float a[6] = {a01.x, a01.y, a23.x, a23.y, a45.x, a45.y};
    float s, b[6];
    rotor_from_angles(a, s, b);
    float* vp = val + (size_t)row * D_DIM + k * 4;
    float4 v4 = *(const float4*)vp;
    float v[4] = {v4.x, v4.y, v4.z, v4.w}, o[4];
    apply_rotor(s, b, v, o);
    *(float4*)vp = make_float4(o[0], o[1], o[2], o[3]);
}

// ---------------- scan phase 1: per-chunk sums ----------------
__global__ __launch_bounds__(256)
void chunk_sum_kernel(const float* __restrict__ rot, float4* __restrict__ sums)
{
    int bc = blockIdx.x;
    int b = bc >> 8, c = bc & 255;
    int k = threadIdx.x;
    const float* p = rot + ((size_t)(b * L_DIM + c * CHUNK_LEN)) * D_DIM + k * 4;
    float4 acc = make_float4(0.f, 0.f, 0.f, 0.f);
    #pragma unroll
    for (int i = 0; i < CHUNK_LEN; ++i) {
        float4 v = *(const float4*)(p + (size_t)i * D_DIM);
        acc.x += v.x; acc.y += v.y; acc.z += v.z; acc.w += v.w;
    }
    sums[(size_t)bc * 256 + k] = acc;
}

// ---------------- scan phase 2: exclusive scan of chunk sums ----------------
__global__ __launch_bounds__(256)
void scan_chunks_kernel(const float4* __restrict__ sums, float4* __restrict__ carry)
{
    int b = blockIdx.x >> 8;
    int k = blockIdx.x & 255;
    int c = threadIdx.x;
    __shared__ float4 sh[CHUNKS];
    float4 v = sums[((size_t)(b * CHUNKS + c)) * 256 + k];
    sh[c] = v;
    __syncthreads();
    for (int off = 1; off < CHUNKS; off <<= 1) {
        float4 t = make_float4(0.f, 0.f, 0.f, 0.f);
        if (c >= off) t = sh[c - off];
        __syncthreads();
        v.x += t.x; v.y += t.y; v.z += t.z; v.w += t.w;
        sh[c] = v;
        __syncthreads();
    }
    float4 ex = make_float4(0.f, 0.f, 0.f, 0.f);
    if (c > 0) ex = sh[c - 1];
    carry[((size_t)(b * CHUNKS + c)) * 256 + k] = ex;
}

// ---------------- scan phase 3: running sum + reversed query rotor + 1/sqrt(t) ----------------
__global__ __launch_bounds__(256)
void scan_apply_kernel(const float* __restrict__ rot, const float4* __restrict__ carry,
                       const float* __restrict__ qang, float* __restrict__ outr)
{
    int bc = blockIdx.x;
    int b = bc >> 8, c = bc & 255;
    int k = threadIdx.x;
    float4 run = carry[(size_t)bc * 256 + k];
    for (int i = 0; i < CHUNK_LEN; ++i) {
        int l = c * CHUNK_LEN + i;
        size_t roff = ((size_t)(b * L_DIM + l)) * D_DIM + k * 4;
        float4 rv = *(const float4*)(rot + roff);
        run.x += rv.x; run.y += rv.y; run.z += rv.z; run.w += rv.w;
        const float* ap = qang + ((size_t)(b * L_DIM + l)) * N6 + k * 6;
        float2 a01 = *(const float2*)(ap);
        float2 a23 = *(const float2*)(ap + 2);
        float2 a45 = *(const float2*)(ap + 4);
        float a[6] = {a01.x, a01.y, a23.x, a23.y, a45.x, a45.y};
        float s, bb[6];
        rotor_from_angles(a, s, bb);
        #pragma unroll
        for (int t = 0; t < 6; ++t) bb[t] = -bb[t];
        float mem[4] = {run.x, run.y, run.z, run.w}, o[4];
        apply_rotor(s, bb, mem, o);
        float inv = 1.0f / sqrtf((float)(l + 1));
        *(float4*)(outr + roff) = make_float4(o[0] * inv, o[1] * inv, o[2] * inv, o[3] * inv);
    }
}

// ---------------- LayerNorm: fp32 in -> bf16 out ----------------
__global__ __launch_bounds__(256)
void layernorm_kernel(const float* __restrict__ r, const float* __restrict__ g,
                      const float* __restrict__ b, __hip_bfloat16* __restrict__ out)
{
    int row = blockIdx.x;
    int t = threadIdx.x;
    const float* p = r + (size_t)row * D_DIM + t * 4;
    float4 v = *(const float4*)p;
    float s = v.x + v.y + v.z + v.w;
    float q = v.x * v.x + v.y * v.y + v.z * v.z + v.w * v.w;
    #pragma unroll
    for (int off = 1; off < 64; off <<= 1) {
        s += __shfl_xor(s, off);
        q += __shfl_xor(q, off);
    }
    __shared__ float ss[4], qq[4];
    int wave = t >> 6, lane = t & 63;
    if (lane == 0) { ss[wave] = s; qq[wave] = q; }
    __syncthreads();
    s = ss[0] + ss[1] + ss[2] + ss[3];
    q = qq[0] + qq[1] + qq[2] + qq[3];
    float mu = s * (1.0f / 1024.0f);
    float var = q * (1.0f / 1024.0f) - mu * mu;
    float rstd = 1.0f / sqrtf(var + 1e-5f);
    float4 gv = *(const float4*)(g + t * 4);
    float4 bv = *(const float4*)(b + t * 4);
    ushort4 pk;
    pk.x = f2bf((v.x - mu) * rstd * gv.x + bv.x);
    pk.y = f2bf((v.y - mu) * rstd * gv.y + bv.y);
    pk.z = f2bf((v.z - mu) * rstd * gv.z + bv.z);
    pk.w = f2bf((v.w - mu) * rstd * gv.w + bv.w);
    *(ushort4*)(out + (size_t)row * D_DIM + t * 4) = pk;
}

extern "C" void kernel_launch(void* const* d_in, const int* in_sizes, int n_in,
                              void* d_out, int out_size, void* d_ws, size_t ws_size,
                              hipStream_t stream)
{
    const float* x   = (const float*)d_in[0];
    const float* wk1 = (const float*)d_in[1];
    const float* bk1 = (const float*)d_in[2];
    const float* wk2 = (const float*)d_in[3];
    const float* bk2 = (const float*)d_in[4];
    const float* wq1 = (const float*)d_in[5];
    const float* bq1 = (const float*)d_in[6];
    const float* wq2 = (const float*)d_in[7];
    const float* bq2 = (const float*)d_in[8];
    const float* wv  = (const float*)d_in[9];
    const float* bv  = (const float*)d_in[10];
    const float* lng = (const float*)d_in[11];
    const float* lnb = (const float*)d_in[12];
    const float* wo  = (const float*)d_in[13];
    const float* bo  = (const float*)d_in[14];
    float* out = (float*)d_out;

    char* ws = (char*)d_ws;
    float*  angles = (float*)ws;                             // 48 MB [0,48)
    float*  val    = (float*)(ws + (48ull << 20));           // 32 MB [48,80)
    float4* sums   = (float4*)(ws + (80ull << 20));          // 2 MB
    float4* carry  = (float4*)(ws + (82ull << 20));          // 2 MB
    __hip_bfloat16* xb   = (__hip_bfloat16*)(ws + (84ull  << 20)); // 16 MB (later: rn)
    __hip_bfloat16* H    = (__hip_bfloat16*)(ws + (100ull << 20)); // 16 MB (hk/hq)
    __hip_bfloat16* wk1t = (__hip_bfloat16*)(ws + (116ull << 20)); // 2 MB
    __hip_bfloat16* wq1t = (__hip_bfloat16*)(ws + (118ull << 20)); // 2 MB
    __hip_bfloat16* wvt  = (__hip_bfloat16*)(ws + (120ull << 20)); // 2 MB
    __hip_bfloat16* wot  = (__hip_bfloat16*)(ws + (122ull << 20)); // 2 MB
    __hip_bfloat16* wk2t = (__hip_bfloat16*)(ws + (124ull << 20)); // 3 MB
    __hip_bfloat16* wq2t = (__hip_bfloat16*)(ws + (127ull << 20)); // 3 MB
    __hip_bfloat16* rn   = xb;                                     // alias, x no longer needed in bf16

    dim3 blk(256);
    dim3 gt1(D_DIM / 32, D_DIM / 32);
    dim3 gt2(N6 / 32, D_DIM / 32);
    transpose_cvt_kernel<<<gt1, blk, 0, stream>>>(wk1, wk1t, D_DIM, D_DIM);
    transpose_cvt_kernel<<<gt1, blk, 0, stream>>>(wq1, wq1t, D_DIM, D_DIM);
    transpose_cvt_kernel<<<gt1, blk, 0, stream>>>(wv,  wvt,  D_DIM, D_DIM);
    transpose_cvt_kernel<<<gt1, blk, 0, stream>>>(wo,  wot,  D_DIM, D_DIM);
    transpose_cvt_kernel<<<gt2, blk, 0, stream>>>(wk2, wk2t, D_DIM, N6);
    transpose_cvt_kernel<<<gt2, blk, 0, stream>>>(wq2, wq2t, D_DIM, N6);
    cvt_bf16_kernel<<<dim3(M_ROWS * D_DIM / (256 * 8)), blk, 0, stream>>>(x, xb);

    dim3 gg1(M_ROWS / 128, D_DIM / 128);   // (64, 8)
    dim3 gg2(M_ROWS / 128, N6 / 128);      // (64, 12)

    // hk = gelu(x@wk1 + bk1)  [bf16]
    mfma_gemm_kernel<1, 1><<<gg1, blk, 0, stream>>>(xb, wk1t, bk1, nullptr, H, M_ROWS, D_DIM, D_DIM);
    // ak = tanh(hk@wk2 + bk2) * pi/2  [f32]
    mfma_gemm_kernel<2, 0><<<gg2, blk, 0, stream>>>(H, wk2t, bk2, nullptr, angles, M_ROWS, N6, D_DIM);
    // value = x@wv + bv  [f32]
    mfma_gemm_kernel<0, 0><<<gg1, blk, 0, stream>>>(xb, wvt, bv, nullptr, val, M_ROWS, D_DIM, D_DIM);
    // rotated = apply_rotor(rotor(ak), value)  (in place)
    rotate_value_kernel<<<dim3(M_ROWS * K_DIM / 256), blk, 0, stream>>>(angles, val);
    // hq = gelu(x@wq1 + bq1)  [bf16]
    mfma_gemm_kernel<1, 1><<<gg1, blk, 0, stream>>>(xb, wq1t, bq1, nullptr, H, M_ROWS, D_DIM, D_DIM);
    // aq = tanh(hq@wq2 + bq2) * pi/2  [f32]
    mfma_gemm_kernel<2, 0><<<gg2, blk, 0, stream>>>(H, wq2t, bq2, nullptr, angles, M_ROWS, N6, D_DIM);
    // cumsum + reversed query rotor + 1/sqrt(t)  (in place on val)
    chunk_sum_kernel<<<dim3(B_DIM * CHUNKS), blk, 0, stream>>>(val, sums);
    scan_chunks_kernel<<<dim3(B_DIM * K_DIM), blk, 0, stream>>>(sums, carry);
    scan_apply_kernel<<<dim3(B_DIM * CHUNKS), blk, 0, stream>>>(val, carry, angles, val);
    // LayerNorm -> bf16 rn
    layernorm_kernel<<<dim3(M_ROWS), blk, 0, stream>>>(val, lng, lnb, rn);
    // out = x + rn@wo + bo
    mfma_gemm_kernel<0, 2><<<gg1, blk, 0, stream>>>(rn, wot, bo, x, out, M_ROWS, D_DIM, D_DIM);
}

// Round 3
// 269.957 us; speedup vs baseline: 5.7231x; 1.1452x over previous
//
#include <hip/hip_runtime.h>
#include <hip/hip_bf16.h>
#include <math.h>

#define D_DIM 1024
#define L_DIM 4096
#define B_DIM 2
#define K_DIM 256           // D/4
#define N6    1536          // K*6
#define M_ROWS 8192         // B*L
#define CHUNKS 256
#define CHUNK_LEN 16
#define HALF_PI 1.57079632679489662f

typedef __attribute__((ext_vector_type(8))) short short8;
typedef __attribute__((ext_vector_type(4))) float f32x4;
typedef unsigned short us;

__device__ __forceinline__ void gload_lds16(const void* g, void* l) {
    __builtin_amdgcn_global_load_lds(
        (const __attribute__((address_space(1))) unsigned int*)g,
        (__attribute__((address_space(3))) unsigned int*)l,
        16, 0, 0);
}
__device__ __forceinline__ float bf2f(us u) {
    union { unsigned int i; float f; } c; c.i = ((unsigned int)u) << 16; return c.f;
}
__device__ __forceinline__ us f2bf(float v) {
    __hip_bfloat16 h = __float2bfloat16(v);
    return *(us*)&h;
}
__device__ __forceinline__ float tanh_fast(float x) {
    return 1.0f - 2.0f / (1.0f + __expf(2.0f * x));
}
__device__ __forceinline__ float gelu_exact(float v) {
    return 0.5f * v * (1.0f + erff(v * 0.70710678118654752f));
}

// ---------------- rotor helpers ----------------
__device__ __forceinline__ void rotor_from_angles(const float a[6], float& s, float b[6]) {
    float m2 = a[0]*a[0] + a[1]*a[1] + a[2]*a[2] + a[3]*a[3] + a[4]*a[4] + a[5]*a[5];
    float mag = fmaxf(sqrtf(m2), 1e-8f);
    s = __cosf(mag);                 // mag <= pi/2*sqrt(6) ~ 3.85, in fast range
    float f = __sinf(mag) / mag;
    #pragma unroll
    for (int i = 0; i < 6; ++i) b[i] = f * a[i];
}
__device__ __forceinline__ void apply_rotor(float s, const float b[6], const float v[4], float o[4]) {
    float t12 = b[0], t13 = b[1], t14 = b[2], t23 = b[3], t24 = b[4], t34 = b[5];
    float v1 = v[0], v2 = v[1], v3 = v[2], v4 = v[3];
    float s2 = s * s;
    float ts = 2.0f * s;
    o[0] = v1 * (s2 - t12*t12 - t13*t13 - t14*t14) + ts * ( v2*t12 + v3*t13 + v4*t14);
    o[1] = v2 * (s2 - t12*t12 - t23*t23 - t24*t24) + ts * (-v1*t12 + v3*t23 + v4*t24);
    o[2] = v3 * (s2 - t13*t13 - t23*t23 - t34*t34) + ts * (-v1*t13 - v2*t23 + v4*t34);
    o[3] = v4 * (s2 - t14*t14 - t24*t24 - t34*t34) + ts * (-v1*t14 - v2*t24 - v3*t34);
}

// ---------------- weight transpose + bf16 convert: W[K][N] -> Wt[N][K] ----------------
__global__ __launch_bounds__(256)
void transpose_cvt_kernel(const float* __restrict__ W, us* __restrict__ Wt, int Kd, int N)
{
    __shared__ float sh[32][33];
    int n0 = blockIdx.x * 32, k0 = blockIdx.y * 32;
    int tx = threadIdx.x & 31, ty = threadIdx.x >> 5;
    #pragma unroll
    for (int i = 0; i < 32; i += 8)
        sh[ty + i][tx] = W[(size_t)(k0 + ty + i) * N + n0 + tx];
    __syncthreads();
    #pragma unroll
    for (int i = 0; i < 32; i += 8)
        Wt[(size_t)(n0 + ty + i) * Kd + k0 + tx] = f2bf(sh[tx][ty + i]);
}

// ---------------- fp32 -> bf16 convert ----------------
__global__ __launch_bounds__(256)
void cvt_bf16_kernel(const float* __restrict__ in, us* __restrict__ out)
{
    size_t i = ((size_t)blockIdx.x * 256 + threadIdx.x) * 8;
    float4 v0 = *(const float4*)(in + i);
    float4 v1 = *(const float4*)(in + i + 4);
    union { us u[8]; uint4 v; } pk;
    pk.u[0] = f2bf(v0.x); pk.u[1] = f2bf(v0.y); pk.u[2] = f2bf(v0.z); pk.u[3] = f2bf(v0.w);
    pk.u[4] = f2bf(v1.x); pk.u[5] = f2bf(v1.y); pk.u[6] = f2bf(v1.z); pk.u[7] = f2bf(v1.w);
    *(uint4*)(out + i) = pk.v;
}

// ---------------- GEMM core: 128x128 tile, BK=32, 2-phase dbuf, swizzled LDS ----------------
// LDS layout per buffer: [128 rows][32 shorts], 16B chunk c of row r holds logical
// k-chunk (c ^ ((r>>1)&3)). Source pre-swizzled, gload_lds dest linear (rule 21).
__device__ __forceinline__ void gemm_core(
    const us* __restrict__ A, const us* __restrict__ Bt, int Kd,
    int bm, int bn, short* As, short* Bs, f32x4 acc[4][4])
{
    const int tid = threadIdx.x;
    const int l = tid & 63, w = tid >> 6;
    const int wr = w >> 1, wc = w & 1;
    const int srow = tid >> 2, schk = tid & 3;
    const int kch = schk ^ ((srow >> 1) & 3);
    const us* gA0 = A + (size_t)(bm + srow) * Kd + kch * 8;
    const us* gA1 = gA0 + (size_t)64 * Kd;
    const us* gB0 = Bt + (size_t)(bn + srow) * Kd + kch * 8;
    const us* gB1 = gB0 + (size_t)64 * Kd;
    short* dA0 = As + tid * 8;
    short* dA1 = As + 2048 + tid * 8;
    short* dB0 = Bs + tid * 8;
    short* dB1 = Bs + 2048 + tid * 8;

    const int fr = l & 15, fq = l >> 4;
    const int swz = fq ^ ((fr >> 1) & 3);
    const int aoff = (wr * 64 + fr) * 32 + swz * 8;
    const int boff = (wc * 64 + fr) * 32 + swz * 8;

    #pragma unroll
    for (int i = 0; i < 4; ++i)
        #pragma unroll
        for (int j = 0; j < 4; ++j)
            acc[i][j] = (f32x4){0.f, 0.f, 0.f, 0.f};

    const int nk = Kd >> 5;
    gload_lds16(gA0, dA0); gload_lds16(gA1, dA1);
    gload_lds16(gB0, dB0); gload_lds16(gB1, dB1);
    __syncthreads();
    int cur = 0;
    for (int t = 0; t < nk - 1; ++t) {
        const int k0 = (t + 1) * 32;
        const int nb = cur ^ 1;
        gload_lds16(gA0 + k0, dA0 + nb * 4096);
        gload_lds16(gA1 + k0, dA1 + nb * 4096);
        gload_lds16(gB0 + k0, dB0 + nb * 4096);
        gload_lds16(gB1 + k0, dB1 + nb * 4096);
        short8 af[4], bw[4];
        #pragma unroll
        for (int i = 0; i < 4; ++i) {
            af[i] = *(const short8*)&As[cur * 4096 + aoff + i * 512];
            bw[i] = *(const short8*)&Bs[cur * 4096 + boff + i * 512];
        }
        #pragma unroll
        for (int i = 0; i < 4; ++i)
            #pragma unroll
            for (int j = 0; j < 4; ++j)
                acc[i][j] = __builtin_amdgcn_mfma_f32_16x16x32_bf16(bw[j], af[i], acc[i][j], 0, 0, 0);
        __syncthreads();   // drains vmcnt (next tile staged) + guards buffer reuse
        cur ^= 1;
    }
    {   // final tile
        short8 af[4], bw[4];
        #pragma unroll
        for (int i = 0; i < 4; ++i) {
            af[i] = *(const short8*)&As[cur * 4096 + aoff + i * 512];
            bw[i] = *(const short8*)&Bs[cur * 4096 + boff + i * 512];
        }
        #pragma unroll
        for (int i = 0; i < 4; ++i)
            #pragma unroll
            for (int j = 0; j < 4; ++j)
                acc[i][j] = __builtin_amdgcn_mfma_f32_16x16x32_bf16(bw[j], af[i], acc[i][j], 0, 0, 0);
    }
    // with swapped operands, lane holds row = bm+wr*64+i*16+fr,
    // cols = bn+wc*64+j*16+fq*4+{0..3}  (4 consecutive cols -> packed stores)
}

// ---------------- GEMM A: x @ [wk1|wq1|wv], fused epilogues, bf16 out ----------------
__global__ __launch_bounds__(256)
void gemm_fused3(const us* __restrict__ xb,
                 const us* __restrict__ w0t, const us* __restrict__ w1t, const us* __restrict__ w2t,
                 const float* __restrict__ b0, const float* __restrict__ b1, const float* __restrict__ b2,
                 us* __restrict__ o0, us* __restrict__ o1, us* __restrict__ o2)
{
    __shared__ short As[2 * 4096];
    __shared__ short Bs[2 * 4096];
    const int bm = blockIdx.x * 128;
    const int r = blockIdx.y >> 3;            // 0=k,1=q,2=v
    const int bn = (blockIdx.y & 7) * 128;
    const us* Bt = (r == 0) ? w0t : (r == 1) ? w1t : w2t;
    const float* bias = (r == 0) ? b0 : (r == 1) ? b1 : b2;
    us* outp = (r == 0) ? o0 : (r == 1) ? o1 : o2;
    f32x4 acc[4][4];
    gemm_core(xb, Bt, D_DIM, bm, bn, As, Bs, acc);
    const int l = threadIdx.x & 63, w = threadIdx.x >> 6;
    const int wr = w >> 1, wc = w & 1, fr = l & 15, fq = l >> 4;
    #pragma unroll
    for (int i = 0; i < 4; ++i) {
        int row = bm + wr * 64 + i * 16 + fr;
        #pragma unroll
        for (int j = 0; j < 4; ++j) {
            int colb = bn + wc * 64 + j * 16 + fq * 4;
            float4 bs = *(const float4*)(bias + colb);
            float v0 = acc[i][j][0] + bs.x, v1 = acc[i][j][1] + bs.y;
            float v2 = acc[i][j][2] + bs.z, v3 = acc[i][j][3] + bs.w;
            if (r < 2) { v0 = gelu_exact(v0); v1 = gelu_exact(v1); v2 = gelu_exact(v2); v3 = gelu_exact(v3); }
            ushort4 pk; pk.x = f2bf(v0); pk.y = f2bf(v1); pk.z = f2bf(v2); pk.w = f2bf(v3);
            *(ushort4*)(outp + (size_t)row * D_DIM + colb) = pk;
        }
    }
}

// ---------------- GEMM B (batched z=2): angles = tanh(H @ w2 + b2)*pi/2, bf16 out ----------------
__global__ __launch_bounds__(256)
void gemm_angles(const us* __restrict__ Hk, const us* __restrict__ Hq,
                 const us* __restrict__ wk2t, const us* __restrict__ wq2t,
                 const float* __restrict__ bk2, const float* __restrict__ bq2,
                 us* __restrict__ ak, us* __restrict__ aq)
{
    __shared__ short As[2 * 4096];
    __shared__ short Bs[2 * 4096];
    const int z = blockIdx.z;
    const us* A  = z ? Hq : Hk;
    const us* Bt = z ? wq2t : wk2t;
    const float* bias = z ? bq2 : bk2;
    us* outp = z ? aq : ak;
    const int bm = blockIdx.x * 128;
    const int bn = blockIdx.y * 128;
    f32x4 acc[4][4];
    gemm_core(A, Bt, D_DIM, bm, bn, As, Bs, acc);
    const int l = threadIdx.x & 63, w = threadIdx.x >> 6;
    const int wr = w >> 1, wc = w & 1, fr = l & 15, fq = l >> 4;
    #pragma unroll
    for (int i = 0; i < 4; ++i) {
        int row = bm + wr * 64 + i * 16 + fr;
        #pragma unroll
        for (int j = 0; j < 4; ++j) {
            int colb = bn + wc * 64 + j * 16 + fq * 4;
            float4 bs = *(const float4*)(bias + colb);
            ushort4 pk;
            pk.x = f2bf(tanh_fast(acc[i][j][0] + bs.x) * HALF_PI);
            pk.y = f2bf(tanh_fast(acc[i][j][1] + bs.y) * HALF_PI);
            pk.z = f2bf(tanh_fast(acc[i][j][2] + bs.z) * HALF_PI);
            pk.w = f2bf(tanh_fast(acc[i][j][3] + bs.w) * HALF_PI);
            *(ushort4*)(outp + (size_t)row * N6 + colb) = pk;
        }
    }
}

// ---------------- GEMM C: out = x + rn @ wo + bo, fp32 out ----------------
__global__ __launch_bounds__(256)
void gemm_final(const us* __restrict__ rn, const us* __restrict__ wot,
                const float* __restrict__ bo, const float* __restrict__ x,
                float* __restrict__ out)
{
    __shared__ short As[2 * 4096];
    __shared__ short Bs[2 * 4096];
    const int bm = blockIdx.x * 128;
    const int bn = blockIdx.y * 128;
    f32x4 acc[4][4];
    gemm_core(rn, wot, D_DIM, bm, bn, As, Bs, acc);
    const int l = threadIdx.x & 63, w = threadIdx.x >> 6;
    const int wr = w >> 1, wc = w & 1, fr = l & 15, fq = l >> 4;
    #pragma unroll
    for (int i = 0; i < 4; ++i) {
        int row = bm + wr * 64 + i * 16 + fr;
        #pragma unroll
        for (int j = 0; j < 4; ++j) {
            int colb = bn + wc * 64 + j * 16 + fq * 4;
            size_t off = (size_t)row * D_DIM + colb;
            float4 bs = *(const float4*)(bo + colb);
            float4 rx = *(const float4*)(x + off);
            float4 o;
            o.x = acc[i][j][0] + bs.x + rx.x;
            o.y = acc[i][j][1] + bs.y + rx.y;
            o.z = acc[i][j][2] + bs.z + rx.z;
            o.w = acc[i][j][3] + bs.w + rx.w;
            *(float4*)(out + off) = o;
        }
    }
}

// ---------------- scan phase 1: rotate(value by key rotor) + per-chunk sums ----------------
__global__ __launch_bounds__(256)
void rot_chunk_sum(const us* __restrict__ value, const us* __restrict__ ak,
                   float4* __restrict__ sums)
{
    int bc = blockIdx.x;
    int b = bc >> 8, c = bc & 255;
    int k = threadIdx.x;
    float4 acc = make_float4(0.f, 0.f, 0.f, 0.f);
    size_t row0 = (size_t)b * L_DIM + c * CHUNK_LEN;
    for (int i = 0; i < CHUNK_LEN; ++i) {
        size_t row = row0 + i;
        ushort4 uv = *(const ushort4*)(value + row * D_DIM + k * 4);
        const unsigned int* ap = (const unsigned int*)(ak + row * N6 + k * 6);
        unsigned int a0 = ap[0], a1 = ap[1], a2 = ap[2];
        float a[6] = { bf2f(a0 & 0xffff), bf2f(a0 >> 16), bf2f(a1 & 0xffff),
                       bf2f(a1 >> 16), bf2f(a2 & 0xffff), bf2f(a2 >> 16) };
        float s, bb[6];
        rotor_from_angles(a, s, bb);
        float v[4] = {bf2f(uv.x), bf2f(uv.y), bf2f(uv.z), bf2f(uv.w)}, o[4];
        apply_rotor(s, bb, v, o);
        acc.x += o[0]; acc.y += o[1]; acc.z += o[2]; acc.w += o[3];
    }
    sums[(size_t)bc * 256 + k] = acc;
}

// ---------------- scan phase 2: exclusive scan of chunk sums ----------------
__global__ __launch_bounds__(256)
void scan_chunks_kernel(const float4* __restrict__ sums, float4* __restrict__ carry)
{
    int b = blockIdx.x >> 8;
    int k = blockIdx.x & 255;
    int c = threadIdx.x;
    __shared__ float4 sh[CHUNKS];
    float4 v = sums[((size_t)(b * CHUNKS + c)) * 256 + k];
    sh[c] = v;
    __syncthreads();
    for (int off = 1; off < CHUNKS; off <<= 1) {
        float4 t = make_float4(0.f, 0.f, 0.f, 0.f);
        if (c >= off) t = sh[c - off];
        __syncthreads();
        v.x += t.x; v.y += t.y; v.z += t.z; v.w += t.w;
        sh[c] = v;
        __syncthreads();
    }
    float4 ex = make_float4(0.f, 0.f, 0.f, 0.f);
    if (c > 0) ex = sh[c - 1];
    carry[((size_t)(b * CHUNKS + c)) * 256 + k] = ex;
}

// ---------------- scan phase 3: rotate+cumsum + reversed query rotor + 1/sqrt + LayerNorm ----------------
__global__ __launch_bounds__(256)
void scan_apply_ln(const us* __restrict__ value, const us* __restrict__ ak,
                   const us* __restrict__ aq, const float4* __restrict__ carry,
                   const float* __restrict__ g, const float* __restrict__ bta,
                   us* __restrict__ rn)
{
    int bc = blockIdx.x;
    int b = bc >> 8, c = bc & 255;
    int k = threadIdx.x;
    int wv = k >> 6, lane = k & 63;
    float4 run = carry[(size_t)bc * 256 + k];
    float4 gv = *(const float4*)(g + k * 4);
    float4 bv = *(const float4*)(bta + k * 4);
    __shared__ float reds[4], redq[4];
    for (int i = 0; i < CHUNK_LEN; ++i) {
        int l = c * CHUNK_LEN + i;
        size_t row = (size_t)b * L_DIM + l;
        // key rotation + running sum
        ushort4 uv = *(const ushort4*)(value + row * D_DIM + k * 4);
        const unsigned int* akp = (const unsigned int*)(ak + row * N6 + k * 6);
        unsigned int ka0 = akp[0], ka1 = akp[1], ka2 = akp[2];
        float a[6] = { bf2f(ka0 & 0xffff), bf2f(ka0 >> 16), bf2f(ka1 & 0xffff),
                       bf2f(ka1 >> 16), bf2f(ka2 & 0xffff), bf2f(ka2 >> 16) };
        float s, bb[6];
        rotor_from_angles(a, s, bb);
        float v[4] = {bf2f(uv.x), bf2f(uv.y), bf2f(uv.z), bf2f(uv.w)}, o[4];
        apply_rotor(s, bb, v, o);
        run.x += o[0]; run.y += o[1]; run.z += o[2]; run.w += o[3];
        // reversed query rotor
        const unsigned int* aqp = (const unsigned int*)(aq + row * N6 + k * 6);
        unsigned int qa0 = aqp[0], qa1 = aqp[1], qa2 = aqp[2];
        float aq6[6] = { bf2f(qa0 & 0xffff), bf2f(qa0 >> 16), bf2f(qa1 & 0xffff),
                         bf2f(qa1 >> 16), bf2f(qa2 & 0xffff), bf2f(qa2 >> 16) };
        float qs, qb[6];
        rotor_from_angles(aq6, qs, qb);
        #pragma unroll
        for (int t = 0; t < 6; ++t) qb[t] = -qb[t];
        float mem[4] = {run.x, run.y, run.z, run.w}, o2[4];
        apply_rotor(qs, qb, mem, o2);
        float inv = rsqrtf((float)(l + 1));
        o2[0] *= inv; o2[1] *= inv; o2[2] *= inv; o2[3] *= inv;
        // fused LayerNorm over the row (block holds all 1024 elements)
        float sm = o2[0] + o2[1] + o2[2] + o2[3];
        float qm = o2[0]*o2[0] + o2[1]*o2[1] + o2[2]*o2[2] + o2[3]*o2[3];
        #pragma unroll
        for (int off = 1; off < 64; off <<= 1) {
            sm += __shfl_xor(sm, off);
            qm += __shfl_xor(qm, off);
        }
        if (lane == 0) { reds[wv] = sm; redq[wv] = qm; }
        __syncthreads();
        sm = reds[0] + reds[1] + reds[2] + reds[3];
        qm = redq[0] + redq[1] + redq[2] + redq[3];
        float mu = sm * (1.0f / 1024.0f);
        float var = qm * (1.0f / 1024.0f) - mu * mu;
        float rstd = rsqrtf(var + 1e-5f);
        ushort4 pk;
        pk.x = f2bf((o2[0] - mu) * rstd * gv.x + bv.x);
        pk.y = f2bf((o2[1] - mu) * rstd * gv.y + bv.y);
        pk.z = f2bf((o2[2] - mu) * rstd * gv.z + bv.z);
        pk.w = f2bf((o2[3] - mu) * rstd * gv.w + bv.w);
        *(ushort4*)(rn + row * D_DIM + k * 4) = pk;
        __syncthreads();   // reds/redq reuse guard
    }
}

extern "C" void kernel_launch(void* const* d_in, const int* in_sizes, int n_in,
                              void* d_out, int out_size, void* d_ws, size_t ws_size,
                              hipStream_t stream)
{
    const float* x   = (const float*)d_in[0];
    const float* wk1 = (const float*)d_in[1];
    const float* bk1 = (const float*)d_in[2];
    const float* wk2 = (const float*)d_in[3];
    const float* bk2 = (const float*)d_in[4];
    const float* wq1 = (const float*)d_in[5];
    const float* bq1 = (const float*)d_in[6];
    const float* wq2 = (const float*)d_in[7];
    const float* bq2 = (const float*)d_in[8];
    const float* wv  = (const float*)d_in[9];
    const float* bv  = (const float*)d_in[10];
    const float* lng = (const float*)d_in[11];
    const float* lnb = (const float*)d_in[12];
    const float* wo  = (const float*)d_in[13];
    const float* bo  = (const float*)d_in[14];
    float* out = (float*)d_out;

    char* ws = (char*)d_ws;
    us* xb    = (us*)(ws);                       // 16 MB [0,16)   (later aliased as rn)
    us* Hk    = (us*)(ws + (16ull  << 20));      // 16 MB
    us* Hq    = (us*)(ws + (32ull  << 20));      // 16 MB
    us* val   = (us*)(ws + (48ull  << 20));      // 16 MB
    us* ak    = (us*)(ws + (64ull  << 20));      // 24 MB
    us* aq    = (us*)(ws + (88ull  << 20));      // 24 MB
    float4* sums  = (float4*)(ws + (112ull << 20)); // 2 MB
    float4* carry = (float4*)(ws + (114ull << 20)); // 2 MB
    us* wk1t  = (us*)(ws + (116ull << 20));      // 2 MB
    us* wq1t  = (us*)(ws + (118ull << 20));      // 2 MB
    us* wvt   = (us*)(ws + (120ull << 20));      // 2 MB
    us* wot   = (us*)(ws + (122ull << 20));      // 2 MB
    us* wk2t  = (us*)(ws + (124ull << 20));      // 3 MB
    us* wq2t  = (us*)(ws + (127ull << 20));      // 3 MB -> 130 MB total
    us* rn    = xb;                              // alias: xb dead after gemm_fused3

    dim3 blk(256);
    dim3 gt1(D_DIM / 32, D_DIM / 32);
    dim3 gt2(N6 / 32, D_DIM / 32);
    transpose_cvt_kernel<<<gt1, blk, 0, stream>>>(wk1, wk1t, D_DIM, D_DIM);
    transpose_cvt_kernel<<<gt1, blk, 0, stream>>>(wq1, wq1t, D_DIM, D_DIM);
    transpose_cvt_kernel<<<gt1, blk, 0, stream>>>(wv,  wvt,  D_DIM, D_DIM);
    transpose_cvt_kernel<<<gt1, blk, 0, stream>>>(wo,  wot,  D_DIM, D_DIM);
    transpose_cvt_kernel<<<gt2, blk, 0, stream>>>(wk2, wk2t, D_DIM, N6);
    transpose_cvt_kernel<<<gt2, blk, 0, stream>>>(wq2, wq2t, D_DIM, N6);
    cvt_bf16_kernel<<<dim3(M_ROWS * D_DIM / (256 * 8)), blk, 0, stream>>>(x, xb);

    // GEMM A: x @ [wk1|wq1|wv] -> Hk, Hq, val (bf16), 1536 blocks
    gemm_fused3<<<dim3(M_ROWS / 128, 24), blk, 0, stream>>>(
        xb, wk1t, wq1t, wvt, bk1, bq1, bv, Hk, Hq, val);
    // GEMM B: angles (batched k/q), 1536 blocks
    gemm_angles<<<dim3(M_ROWS / 128, N6 / 128, 2), blk, 0, stream>>>(
        Hk, Hq, wk2t, wq2t, bk2, bq2, ak, aq);
    // scan chain (rotate recomputed inline; LN fused into phase 3)
    rot_chunk_sum<<<dim3(B_DIM * CHUNKS), blk, 0, stream>>>(val, ak, sums);
    scan_chunks_kernel<<<dim3(B_DIM * K_DIM), blk, 0, stream>>>(sums, carry);
    scan_apply_ln<<<dim3(B_DIM * CHUNKS), blk, 0, stream>>>(val, ak, aq, carry, lng, lnb, rn);
    // GEMM C: out = x + rn @ wo + bo
    gemm_final<<<dim3(M_ROWS / 128, D_DIM / 128), blk, 0, stream>>>(rn, wot, bo, x, out);
}